// Round 6
// baseline (583.644 us; speedup 1.0000x reference)
//
#include <hip/hip_runtime.h>
#include <hip/hip_bf16.h>

#define DD 32   // node/output dim
#define HH 64   // psi hidden
// PSI_IN = 5*32 = 160

typedef __attribute__((ext_vector_type(8))) short bf16x8;   // 8 bf16 = 4 VGPRs
typedef __attribute__((ext_vector_type(4))) float f32x4;
typedef __attribute__((ext_vector_type(4))) unsigned int u32x4;
typedef __attribute__((ext_vector_type(4))) unsigned short us16x4;

static __device__ __forceinline__ unsigned short f2bf(float x) {
    union { float f; unsigned u; } v; v.f = x;
    return (unsigned short)((v.u + 0x7FFFu + ((v.u >> 16) & 1u)) >> 16);
}
static __device__ __forceinline__ float bf2f(unsigned short h) {
    union { unsigned u; float f; } v; v.u = ((unsigned)h) << 16; return v.f;
}
// packed f32x2 -> bf16x2 (v_cvt_pk_bf16_f32), low = a
static __device__ __forceinline__ unsigned pk2(float a, float b) {
    __hip_bfloat162 h = __float22bfloat162_rn(make_float2(a, b));
    union { __hip_bfloat162 h2; unsigned u; } cv; cv.h2 = h; return cv.u;
}

// ======================= weight / node prep =======================

// 34 A-operand weight fragments (transposed MLP: M = out-features).
// 16x16x32 A-frag: lane l (c=l&15, q=l>>4): m = t*16+c, k-slot = q*8+j.
//  f 0..19  wf0 (t=f/5, kk=f%5):  k = kk*32 + q*8 + j                 <- w0[k][m]
//  f 20..27 wf1 (t,kp):           k = kp*32 + (j>>2)*16 + q*4 + (j&3) <- w1[k][m]
//  f 28..31 wf2 (t,kp):           same interleave                     <- w2[k][m]
//  f 32..33 wfW (t):              k = (j>>2)*16 + q*4 + (j&3)         <- W[k][m]
__global__ __launch_bounds__(256) void prep_weights(
    const float* __restrict__ w0, const float* __restrict__ w1,
    const float* __restrict__ w2, const float* __restrict__ W,
    unsigned short* __restrict__ frags)
{
    const int tid = blockIdx.x * 256 + threadIdx.x;
    const int f = tid >> 6, l = tid & 63;
    if (f >= 34) return;
    const int c = l & 15, q = l >> 4;
    unsigned short* dst = frags + f * 512 + l * 8;
    if (f < 20) {
        const int t = f / 5, kk = f % 5, m = t * 16 + c;
        #pragma unroll
        for (int j = 0; j < 8; ++j)
            dst[j] = f2bf(w0[(kk * 32 + q * 8 + j) * HH + m]);
    } else if (f < 28) {
        const int f1 = f - 20, t = f1 >> 1, kp = f1 & 1, m = t * 16 + c;
        #pragma unroll
        for (int j = 0; j < 8; ++j)
            dst[j] = f2bf(w1[(kp * 32 + (j >> 2) * 16 + q * 4 + (j & 3)) * HH + m]);
    } else if (f < 32) {
        const int f2i = f - 28, t = f2i >> 1, kp = f2i & 1, m = t * 16 + c;
        #pragma unroll
        for (int j = 0; j < 8; ++j)
            dst[j] = f2bf(w2[(kp * 32 + (j >> 2) * 16 + q * 4 + (j & 3)) * DD + m]);
    } else {
        const int t = f - 32, m = t * 16 + c;
        #pragma unroll
        for (int j = 0; j < 8; ++j)
            dst[j] = f2bf(W[((j >> 2) * 16 + q * 4 + (j & 3)) * DD + m]);
    }
}

// nt[n] = [h_s[n][0..31] | h_d[n][0..31]] bf16 -> one 128-B block per node
__global__ __launch_bounds__(256) void prep_nodes(
    const float* __restrict__ h_d, const float* __restrict__ h_s,
    unsigned short* __restrict__ nt, int ND)
{
    const int idx = blockIdx.x * 256 + threadIdx.x;
    if (idx >= ND) return;
    const int n = idx >> 5, d = idx & 31;
    nt[(size_t)n * 64 + d]      = f2bf(h_s[idx]);
    nt[(size_t)n * 64 + 32 + d] = f2bf(h_d[idx]);
}

// ======================= counting sort by receiver =======================

__global__ __launch_bounds__(256) void hist_k(
    const int* __restrict__ rcv, int* __restrict__ cnt, int E)
{
    const int i = blockIdx.x * 256 + threadIdx.x;
    if (i < E) atomicAdd(&cnt[rcv[i]], 1);
}

// exclusive scan, level 1: per-block (256 bins), emits block sums
__global__ __launch_bounds__(256) void scan1_k(
    const int* __restrict__ cnt, int* __restrict__ off,
    int* __restrict__ bsum, int n)
{
    __shared__ int sm[256];
    const int t = threadIdx.x, i = blockIdx.x * 256 + t;
    const int v = (i < n) ? cnt[i] : 0;
    sm[t] = v; __syncthreads();
    int x = v;
    for (int s = 1; s < 256; s <<= 1) {
        const int y = (t >= s) ? sm[t - s] : 0;
        __syncthreads();
        x += y; sm[t] = x;
        __syncthreads();
    }
    if (i < n) off[i] = x - v;
    if (t == 255) bsum[blockIdx.x] = x;
}

// level 2: single block scans block sums (nb <= 512)
__global__ __launch_bounds__(512) void scan2_k(
    const int* __restrict__ bsum, int* __restrict__ boff, int nb)
{
    __shared__ int sm[512];
    const int t = threadIdx.x;
    const int v = (t < nb) ? bsum[t] : 0;
    sm[t] = v; __syncthreads();
    int x = v;
    for (int s = 1; s < 512; s <<= 1) {
        const int y = (t >= s) ? sm[t - s] : 0;
        __syncthreads();
        x += y; sm[t] = x;
        __syncthreads();
    }
    if (t < nb) boff[t] = x - v;
}

// level 3: add block offsets
__global__ __launch_bounds__(256) void scan3_k(
    int* __restrict__ off, const int* __restrict__ boff, int n)
{
    const int i = blockIdx.x * 256 + threadIdx.x;
    if (i < n) off[i] += boff[i >> 8];
}

// scatter edges into receiver-sorted order; off becomes the running cursor
__global__ __launch_bounds__(256) void scatter_k(
    const int* __restrict__ snd, const int* __restrict__ rcv,
    int* __restrict__ off, int* __restrict__ sidx, int* __restrict__ ridx,
    int* __restrict__ eidx, int E)
{
    const int i = blockIdx.x * 256 + threadIdx.x;
    if (i >= E) return;
    const int r = rcv[i];
    const int p = atomicAdd(&off[r], 1);
    sidx[p] = snd[i];
    ridx[p] = r;
    eidx[p] = i;
}

// ======================= fused edge kernel =======================

// One wave per 16-edge tile over receiver-sorted edges. Transposed MLP
// (features on M, edges on N), zero inter-layer LDS, fused @W, atomics into
// out (pre-filled with h_d_prev). Weights in LDS; receiver-side gathers and
// atomics are (nearly) sequential thanks to the sort.
__global__ __launch_bounds__(256, 4) void edge_mfma(
    const unsigned short* __restrict__ nt,
    const float* __restrict__ ef,
    const int* __restrict__ sidx, const int* __restrict__ ridx,
    const int* __restrict__ eidx,
    const unsigned short* __restrict__ frags,
    const float* __restrict__ b0, const float* __restrict__ b1,
    const float* __restrict__ b2,
    float* __restrict__ out, int E, int ntiles)
{
    __shared__ __align__(16) unsigned short wlds[32 * 512];   // 32 KB weight frags
    __shared__ __align__(16) unsigned short sbuf[4][16 * 40]; // 5 KB transpose scratch

    const int tid = threadIdx.x;
    const int lane = tid & 63, w = tid >> 6;
    const int c = lane & 15, q = lane >> 4;

    {   // stage weight frags -> LDS
        const u32x4* src = (const u32x4*)frags;
        u32x4* dst = (u32x4*)wlds;
        #pragma unroll
        for (int i = 0; i < 8; ++i) dst[tid + i * 256] = src[tid + i * 256];
    }
    const bf16x8 wfW0 = *(const bf16x8*)(frags + 32 * 512 + lane * 8);
    const bf16x8 wfW1 = *(const bf16x8*)(frags + 33 * 512 + lane * 8);
    __syncthreads();

    f32x4 b0v[4], b1v[4], b2v[2];
    #pragma unroll
    for (int t = 0; t < 4; ++t) b0v[t] = *(const f32x4*)(b0 + t * 16 + q * 4);
    #pragma unroll
    for (int t = 0; t < 4; ++t) b1v[t] = *(const f32x4*)(b1 + t * 16 + q * 4);
    #pragma unroll
    for (int t = 0; t < 2; ++t) b2v[t] = *(const f32x4*)(b2 + t * 16 + q * 4);

    unsigned short* sw = sbuf[w];
    const int nw = gridDim.x * 4;

    for (int tile = blockIdx.x * 4 + w; tile < ntiles; tile += nw) {
        const int base = tile * 16;
        int ii = base + c; if (ii >= E) ii = E - 1;
        const int si = sidx[ii];
        const int ri = ridx[ii];
        const int e  = eidx ? eidx[ii] : ii;

        const unsigned short* bsi = nt + (size_t)si * 64;
        const unsigned short* bri = nt + (size_t)ri * 64;

        // gathers, issued up front
        bf16x8 gs0 = *(const bf16x8*)(bsi + q * 8);          // h_s[si]
        bf16x8 gs1 = *(const bf16x8*)(bri + q * 8);          // h_s[ri]
        bf16x8 gs2 = *(const bf16x8*)(bsi + 32 + q * 8);     // h_d[si]
        bf16x8 gs3 = *(const bf16x8*)(bri + 32 + q * 8);     // h_d[ri]
        const float* s4 = ef + (size_t)e * DD;
        const f32x4 e0v = *(const f32x4*)(s4 + q * 8);
        const f32x4 e1v = *(const f32x4*)(s4 + q * 8 + 4);
        us16x4 dif[2], djf[2];
        #pragma unroll
        for (int t = 0; t < 2; ++t) {
            dif[t] = *(const us16x4*)(bsi + 32 + t * 16 + q * 4);
            djf[t] = *(const us16x4*)(bri + 32 + t * 16 + q * 4);
        }

        // ---- layer 0 ----
        f32x4 c0[4] = {b0v[0], b0v[1], b0v[2], b0v[3]};
        bf16x8 bch[5];
        bch[0] = gs0; bch[1] = gs1; bch[2] = gs2; bch[3] = gs3;
        {
            union { unsigned u[4]; bf16x8 v; } bb;
            bb.u[0] = pk2(e0v[0], e0v[1]); bb.u[1] = pk2(e0v[2], e0v[3]);
            bb.u[2] = pk2(e1v[0], e1v[1]); bb.u[3] = pk2(e1v[2], e1v[3]);
            bch[4] = bb.v;
        }
        #pragma unroll
        for (int kk = 0; kk < 5; ++kk) {
            #pragma unroll
            for (int t = 0; t < 4; ++t) {
                const bf16x8 a = *(const bf16x8*)(wlds + (t * 5 + kk) * 512 + lane * 8);
                c0[t] = __builtin_amdgcn_mfma_f32_16x16x32_bf16(a, bch[kk], c0[t], 0, 0, 0);
            }
        }
        unsigned x1[4][2];
        #pragma unroll
        for (int kt = 0; kt < 4; ++kt) {
            x1[kt][0] = pk2(fmaxf(c0[kt][0], 0.f), fmaxf(c0[kt][1], 0.f));
            x1[kt][1] = pk2(fmaxf(c0[kt][2], 0.f), fmaxf(c0[kt][3], 0.f));
        }

        // ---- layer 1 (dual-16K MFMAs) ----
        f32x4 c1[4] = {b1v[0], b1v[1], b1v[2], b1v[3]};
        #pragma unroll
        for (int kp = 0; kp < 2; ++kp) {
            union { unsigned u[4]; bf16x8 v; } bb;
            bb.u[0] = x1[2 * kp][0];     bb.u[1] = x1[2 * kp][1];
            bb.u[2] = x1[2 * kp + 1][0]; bb.u[3] = x1[2 * kp + 1][1];
            #pragma unroll
            for (int t = 0; t < 4; ++t) {
                const bf16x8 a = *(const bf16x8*)(wlds + (20 + t * 2 + kp) * 512 + lane * 8);
                c1[t] = __builtin_amdgcn_mfma_f32_16x16x32_bf16(a, bb.v, c1[t], 0, 0, 0);
            }
        }
        unsigned x2[4][2];
        #pragma unroll
        for (int kt = 0; kt < 4; ++kt) {
            x2[kt][0] = pk2(fmaxf(c1[kt][0], 0.f), fmaxf(c1[kt][1], 0.f));
            x2[kt][1] = pk2(fmaxf(c1[kt][2], 0.f), fmaxf(c1[kt][3], 0.f));
        }

        // ---- layer 2 ----
        f32x4 c2[2] = {b2v[0], b2v[1]};
        #pragma unroll
        for (int kp = 0; kp < 2; ++kp) {
            union { unsigned u[4]; bf16x8 v; } bb;
            bb.u[0] = x2[2 * kp][0];     bb.u[1] = x2[2 * kp][1];
            bb.u[2] = x2[2 * kp + 1][0]; bb.u[3] = x2[2 * kp + 1][1];
            #pragma unroll
            for (int t = 0; t < 2; ++t) {
                const bf16x8 a = *(const bf16x8*)(wlds + (28 + t * 2 + kp) * 512 + lane * 8);
                c2[t] = __builtin_amdgcn_mfma_f32_16x16x32_bf16(a, bb.v, c2[t], 0, 0, 0);
            }
        }

        // ---- s_ij = relu(psi)*(h_dj - h_di), then fused @W ----
        union { unsigned u[4]; bf16x8 v; } sb;
        #pragma unroll
        for (int t = 0; t < 2; ++t) {
            const float v0 = fmaxf(c2[t][0], 0.f) * (bf2f(djf[t].x) - bf2f(dif[t].x));
            const float v1 = fmaxf(c2[t][1], 0.f) * (bf2f(djf[t].y) - bf2f(dif[t].y));
            const float v2 = fmaxf(c2[t][2], 0.f) * (bf2f(djf[t].z) - bf2f(dif[t].z));
            const float v3 = fmaxf(c2[t][3], 0.f) * (bf2f(djf[t].w) - bf2f(dif[t].w));
            sb.u[2 * t]     = pk2(v0, v1);
            sb.u[2 * t + 1] = pk2(v2, v3);
        }
        const f32x4 zero = {0.f, 0.f, 0.f, 0.f};
        f32x4 c3[2];
        c3[0] = __builtin_amdgcn_mfma_f32_16x16x32_bf16(wfW0, sb.v, zero, 0, 0, 0);
        c3[1] = __builtin_amdgcn_mfma_f32_16x16x32_bf16(wfW1, sb.v, zero, 0, 0, 0);

        // ---- transpose via per-wave scratch -> coalesced atomics ----
        #pragma unroll
        for (int t = 0; t < 2; ++t) {
            uint2 pv;
            pv.x = pk2(c3[t][0], c3[t][1]);
            pv.y = pk2(c3[t][2], c3[t][3]);
            *(uint2*)(sw + c * 40 + t * 16 + q * 4) = pv;
        }
        #pragma unroll
        for (int r = 0; r < 4; ++r) {
            const int er = base + q * 4 + r;
            if (er < E) {
                const int rr = ridx[er];
                const float v0 = bf2f(sw[(q * 4 + r) * 40 + c]);
                const float v1 = bf2f(sw[(q * 4 + r) * 40 + 16 + c]);
                atomicAdd(out + (size_t)rr * DD + c, v0);
                atomicAdd(out + (size_t)rr * DD + 16 + c, v1);
            }
        }
    }
}

extern "C" void kernel_launch(void* const* d_in, const int* in_sizes, int n_in,
                              void* d_out, int out_size, void* d_ws, size_t ws_size,
                              hipStream_t stream) {
    const float* h_d = (const float*)d_in[0];
    const float* h_s = (const float*)d_in[1];
    const float* ef  = (const float*)d_in[2];
    const int*   snd = (const int*)d_in[3];
    const int*   rcv = (const int*)d_in[4];
    const float* w0  = (const float*)d_in[5];
    const float* b0  = (const float*)d_in[6];
    const float* w1  = (const float*)d_in[7];
    const float* b1  = (const float*)d_in[8];
    const float* w2  = (const float*)d_in[9];
    const float* b2  = (const float*)d_in[10];
    const float* W   = (const float*)d_in[11];
    float* out = (float*)d_out;

    const int N = in_sizes[0] / DD;
    const int E = in_sizes[3];
    const int ntiles = (E + 15) / 16;
    const int nb = (N + 255) / 256;

    // ws layout: frags | nt | cnt | off | bsum | boff | sidx | ridx | eidx
    char* p = (char*)d_ws;
    unsigned short* frags = (unsigned short*)p;                 // 34816 B (128-aligned)
    unsigned short* nt    = (unsigned short*)(p + 34816);       // N*128 B
    size_t o = (34816 + (size_t)N * 128 + 127) & ~(size_t)127;
    int* cnt  = (int*)(p + o);  o += (size_t)N * 4;
    int* off  = (int*)(p + o);  o += (size_t)N * 4;
    int* bsum = (int*)(p + o);  o += 2048;
    int* boff = (int*)(p + o);  o += 2048;
    int* sidx = (int*)(p + o);  o += (size_t)E * 4;
    int* ridx = (int*)(p + o);  o += (size_t)E * 4;
    int* eidx = (int*)(p + o);  o += (size_t)E * 4;
    const bool sorted = (o <= ws_size) && (nb <= 512);

    hipMemcpyAsync(out, h_d, (size_t)N * DD * sizeof(float),
                   hipMemcpyDeviceToDevice, stream);
    prep_weights<<<9, 256, 0, stream>>>(w0, w1, w2, W, frags);
    prep_nodes<<<(N * DD + 255) / 256, 256, 0, stream>>>(h_d, h_s, nt, N * DD);

    if (sorted) {
        hipMemsetAsync(cnt, 0, (size_t)N * 4, stream);
        hist_k<<<(E + 255) / 256, 256, 0, stream>>>(rcv, cnt, E);
        scan1_k<<<nb, 256, 0, stream>>>(cnt, off, bsum, N);
        scan2_k<<<1, 512, 0, stream>>>(bsum, boff, nb);
        scan3_k<<<(N + 255) / 256, 256, 0, stream>>>(off, boff, N);
        scatter_k<<<(E + 255) / 256, 256, 0, stream>>>(snd, rcv, off, sidx, ridx, eidx, E);
        edge_mfma<<<1024, 256, 0, stream>>>(nt, ef, sidx, ridx, eidx, frags,
                                            b0, b1, b2, out, E, ntiles);
    } else {
        edge_mfma<<<1024, 256, 0, stream>>>(nt, ef, snd, rcv, nullptr, frags,
                                            b0, b1, b2, out, E, ntiles);
    }
}